// Round 3
// baseline (665.215 us; speedup 1.0000x reference)
//
#include <hip/hip_runtime.h>
#include <math.h>

#define PI_F 3.14159265358979323846f

typedef float2 cpx;

__device__ __forceinline__ cpx cmul(cpx a, cpx b) {
  return make_float2(a.x*b.x - a.y*b.y, a.x*b.y + a.y*b.x);
}

// ================= Kernel A: build the 48 fixed 16x16 unitaries =============
// State convention: flat index bits (b0 b1 b2 b3), qubit w -> mask (8 >> w).

__device__ void rot_rx(cpx* s, float t, int w) {
  float c = cosf(0.5f*t), sn = sinf(0.5f*t);
  int m = 8 >> w;
  for (int i = 0; i < 16; i++) if (!(i & m)) {
    cpx a = s[i], b = s[i|m];
    s[i]   = make_float2(c*a.x + sn*b.y, c*a.y - sn*b.x);   // c*a + (-i sn)*b
    s[i|m] = make_float2(sn*a.y + c*b.x, c*b.y - sn*a.x);   // (-i sn)*a + c*b
  }
}
__device__ void rot_ry(cpx* s, float t, int w) {
  float c = cosf(0.5f*t), sn = sinf(0.5f*t);
  int m = 8 >> w;
  for (int i = 0; i < 16; i++) if (!(i & m)) {
    cpx a = s[i], b = s[i|m];
    s[i]   = make_float2(c*a.x - sn*b.x, c*a.y - sn*b.y);
    s[i|m] = make_float2(sn*a.x + c*b.x, sn*a.y + c*b.y);
  }
}
__device__ void rot_rz(cpx* s, float t, int w) {
  float c = cosf(0.5f*t), sn = sinf(0.5f*t);
  cpx e0 = make_float2(c, -sn), e1 = make_float2(c, sn);
  int m = 8 >> w;
  for (int i = 0; i < 16; i++) s[i] = cmul((i & m) ? e1 : e0, s[i]);
}
__device__ void crx_g(cpx* s, float t, int w0, int w1) {  // control w0, target w1
  float c = cosf(0.5f*t), sn = sinf(0.5f*t);
  int m0 = 8 >> w0, m1 = 8 >> w1;
  for (int i = 0; i < 16; i++) if ((i & m0) && !(i & m1)) {
    cpx a = s[i], b = s[i|m1];
    s[i]    = make_float2(c*a.x + sn*b.y, c*a.y - sn*b.x);
    s[i|m1] = make_float2(sn*a.y + c*b.x, c*b.y - sn*a.x);
  }
}
__device__ void iswap_g(cpx* s, int w0, int w1) {
  int m0 = 8 >> w0, m1 = 8 >> w1;
  for (int i = 0; i < 16; i++) if (!(i & (m0|m1))) {
    cpx a = s[i|m1], b = s[i|m0];
    s[i|m1] = make_float2(-b.y, b.x);   // i * b
    s[i|m0] = make_float2(-a.y, a.x);   // i * a
  }
}
__device__ void swap_g(cpx* s, int w0, int w1) {
  int m0 = 8 >> w0, m1 = 8 >> w1;
  for (int i = 0; i < 16; i++) if (!(i & (m0|m1))) {
    cpx a = s[i|m1]; s[i|m1] = s[i|m0]; s[i|m0] = a;
  }
}
__device__ void toff_g(cpx* s, int w0, int w1, int w2) {
  int m0 = 8 >> w0, m1 = 8 >> w1, m2 = 8 >> w2;
  for (int i = 0; i < 16; i++) if (!(i & (m0|m1|m2))) {
    int a = i|m0|m1, b = a|m2;
    cpx t = s[a]; s[a] = s[b]; s[b] = t;
  }
}
__device__ void h_g(cpx* s, int w) {
  const float r = 0.70710678118654752f;
  int m = 8 >> w;
  for (int i = 0; i < 16; i++) if (!(i & m)) {
    cpx a = s[i], b = s[i|m];
    s[i]   = make_float2(r*(a.x+b.x), r*(a.y+b.y));
    s[i|m] = make_float2(r*(a.x-b.x), r*(a.y-b.y));
  }
}
__device__ void cphase_g(cpx* s, float phi, int w0, int w1) {
  cpx ph = make_float2(cosf(phi), sinf(phi));
  int m0 = 8 >> w0, m1 = 8 >> w1;
  for (int i = 0; i < 16; i++) if ((i & m0) && (i & m1)) s[i] = cmul(ph, s[i]);
}

__global__ __launch_bounds__(64) void build_unitaries(
    const float* __restrict__ w, const float* __restrict__ ew,
    const float* __restrict__ tw, float2* __restrict__ U) {
  int lid = threadIdx.x;
  int g = blockIdx.x * 4 + (lid >> 4);   // 0..47 = qkv*16 + split
  int col = lid & 15;
  cpx s[16];
  for (int i = 0; i < 16; i++) s[i] = make_float2(i == col ? 1.f : 0.f, 0.f);
  const float* wg  = w  + g*12;   // [NL=3][NQ=4]
  const float* ewg = ew + g*12;
  const float* twg = tw + g*12;
  for (int L = 0; L < 3; L++) {
    for (int i = 0; i < 4; i++) {
      float th = wg[L*4+i];
      rot_rx(s, th, i); rot_ry(s, th, i); rot_rz(s, th, i);
    }
    for (int i = 0; i < 4; i++) {
      float te = ewg[L*4+i];
      crx_g(s, te, i, (i+2)&3);
      crx_g(s, te, i, (i+3)&3);
    }
    for (int i = 0; i < 3; i++) iswap_g(s, i, i+1);
    iswap_g(s, 3, 0);
    toff_g(s, 0, 1, 2);
    for (int i = 0; i < 3; i++) crx_g(s, twg[L*4+i], i, i+1);
    crx_g(s, twg[L*4+3], 3, 0);
    // QPE
    for (int i = 0; i < 4; i++) h_g(s, i);
    for (int i = 1; i < 4; i++)
      for (int j = 0; j < i; j++)
        cphase_g(s, PI_F / (float)(1 << (i-j)), j, i);
    swap_g(s, 0, 3);
    swap_g(s, 1, 2);
    for (int i = 0; i < 4; i++) {
      h_g(s, i);
      for (int j = 0; j < i; j++)
        cphase_g(s, -PI_F / (float)(1 << (i-j)), j, i);
    }
  }
  for (int r = 0; r < 16; r++) U[g*256 + r*16 + col] = s[r];
}

// ============ Kernel B: per-token product-state -> expvals ==================
// Q, K written TRANSPOSED: [192][16384]  (d = split*12 + {4Z,4X,4Y})
// V written row-major:     [16384][192]

__global__ __launch_bounds__(256) void qkv_kernel(
    const float* __restrict__ x, const float2* __restrict__ U,
    float* __restrict__ qbuf, float* __restrict__ kbuf,
    float* __restrict__ vbuf) {
  __shared__ cpx Us[256];
  const int tid = threadIdx.x;
  const int g = blockIdx.y;           // 0..47
  Us[tid] = U[g*256 + tid];
  __syncthreads();
  const int bs = blockIdx.x * 256 + tid;   // 0..16383
  const int split = g & 15;
  const int which = g >> 4;                // 0=q 1=k 2=v

  const float4 xv = *reinterpret_cast<const float4*>(x + (size_t)bs*64 + split*4);
  float xa[4] = {xv.x, xv.y, xv.z, xv.w};
  cpx a0[2], a1[2], a2[2], a3[2];
  a0[0] = make_float2(cosf(0.5f*xa[0]), 0.f); a0[1] = make_float2(0.f, -sinf(0.5f*xa[0]));
  a1[0] = make_float2(cosf(0.5f*xa[1]), 0.f); a1[1] = make_float2(0.f, -sinf(0.5f*xa[1]));
  a2[0] = make_float2(cosf(0.5f*xa[2]), 0.f); a2[1] = make_float2(0.f, -sinf(0.5f*xa[2]));
  a3[0] = make_float2(cosf(0.5f*xa[3]), 0.f); a3[1] = make_float2(0.f, -sinf(0.5f*xa[3]));

  cpx p01[4], p23[4], psi[16];
  #pragma unroll
  for (int i = 0; i < 2; i++)
    #pragma unroll
    for (int j = 0; j < 2; j++) {
      p01[i*2+j] = cmul(a0[i], a1[j]);
      p23[i*2+j] = cmul(a2[i], a3[j]);
    }
  #pragma unroll
  for (int i = 0; i < 4; i++)
    #pragma unroll
    for (int j = 0; j < 4; j++)
      psi[i*4+j] = cmul(p01[i], p23[j]);

  cpx po[16];
  #pragma unroll
  for (int r = 0; r < 16; r++) {
    float re = 0.f, im = 0.f;
    #pragma unroll
    for (int c = 0; c < 16; c++) {
      cpx u = Us[r*16+c];
      re += u.x*psi[c].x - u.y*psi[c].y;
      im += u.x*psi[c].y + u.y*psi[c].x;
    }
    po[r] = make_float2(re, im);
  }

  float outv[12];
  #pragma unroll
  for (int q = 0; q < 4; q++) {
    const int m = 8 >> q;
    float z = 0.f, xs = 0.f, ys = 0.f;
    #pragma unroll
    for (int i = 0; i < 16; i++) {
      float pr = po[i].x*po[i].x + po[i].y*po[i].y;
      z += (i & m) ? -pr : pr;
    }
    #pragma unroll
    for (int i = 0; i < 16; i++) if (!(i & m)) {
      cpx aa = po[i], bb = po[i|m];
      xs += aa.x*bb.x + aa.y*bb.y;   // Re(conj(a)*b)
      ys += aa.x*bb.y - aa.y*bb.x;   // Im(conj(a)*b)
    }
    outv[q] = z; outv[4+q] = 2.f*xs; outv[8+q] = 2.f*ys;
  }

  if (which == 2) {                       // V row-major
    float* dst = vbuf + (size_t)bs*192 + split*12;
    *reinterpret_cast<float4*>(dst)     = make_float4(outv[0], outv[1], outv[2],  outv[3]);
    *reinterpret_cast<float4*>(dst + 4) = make_float4(outv[4], outv[5], outv[6],  outv[7]);
    *reinterpret_cast<float4*>(dst + 8) = make_float4(outv[8], outv[9], outv[10], outv[11]);
  } else {                                // Q/K transposed [192][16384]
    float* dst = (which == 0) ? qbuf : kbuf;
    #pragma unroll
    for (int j = 0; j < 12; j++)
      dst[(size_t)(split*12 + j)*16384 + bs] = outv[j];
  }
}

// ====== Kernel C: fused QK^T -> softmax -> attn out -> PV -> layernorm ======
// One block per (batch, 16-row Q tile). 256 threads, static LDS ~60.7 KB.
// grid(16, 64): blockIdx.x = batch (fastest) so the 8-XCD round-robin gives
// each XCD 2 batches -> K/V working set ~3 MB fits per-XCD L2.
// Phase 1: acc[8][8], thread = (ty: 8 rows)x(tx: 8 cols), Kt XOR-swizzled.
// Phase 3: acc_o[8][12], thread = (rg: 8 rows)x(t3: 12 d)x(ks: kk-slice),
//          Vc 16B-block XOR-swizzled by ks, shfl_xor reduce over ks, LN.

#define KTS 1028        // Kt row stride (floats)
#define QTS 20          // Qt row stride

__global__ __launch_bounds__(256, 2) void attn_kernel(
    const float* __restrict__ qbuf, const float* __restrict__ kbuf,
    const float* __restrict__ vbuf, const float* __restrict__ gamma,
    const float* __restrict__ beta, float* __restrict__ out_o,
    float* __restrict__ out_attn) {
  __shared__ float Kt[4 * KTS];       //  4112
  __shared__ float Qt[192 * QTS];     //  3840
  __shared__ float Vc[32 * 192];      //  6144
  __shared__ float Ps[16 * 36];       //   576
  __shared__ float red[512];          //   512  (total 15184 floats = 60736 B)

  const int tid = threadIdx.x;
  const int b  = blockIdx.x;          // batch fastest -> XCD L2 locality
  const int s0 = blockIdx.y * 16;
  const int ty = tid >> 7;     // phase-1 rows 8ty..8ty+7
  const int tx = tid & 127;    // phase-1 cols 8tx..8tx+7

  // ---- Qt staging: qbuf[d][token] -> Qt[d*QTS + r] (r = token - s0) ----
  #pragma unroll
  for (int i = 0; i < 3; i++) {
    int f = tid + 256*i;            // 0..767
    int d = f >> 2, t4 = f & 3;
    float4 q4 = *reinterpret_cast<const float4*>(
        qbuf + (size_t)d*16384 + b*1024 + s0 + 4*t4);
    *reinterpret_cast<float4*>(&Qt[d*QTS + 4*t4]) = q4;
  }

  float acc[8][8];
  #pragma unroll
  for (int r = 0; r < 8; r++)
    #pragma unroll
    for (int c = 0; c < 8; c++) acc[r][c] = 0.f;

  // -------- phase 1: QK^T, 48 d-chunks of 4, software-pipelined --------
  float4 kst[4];
  {
    const int d = tid >> 6, tb = tid & 63;
    #pragma unroll
    for (int i = 0; i < 4; i++)
      kst[i] = *reinterpret_cast<const float4*>(
          kbuf + (size_t)d*16384 + b*1024 + 4*(tb + 64*i));
  }
  const int kblk1 = (2*tx) ^ (((2*tx) >> 3) & 7);
  const int kblk2 = (2*tx+1) ^ (((2*tx+1) >> 3) & 7);

  for (int c = 0; c < 48; c++) {
    __syncthreads();                      // Kt free (incl. Qt ready at c=0)
    {
      const int d = tid >> 6, tb = tid & 63;
      #pragma unroll
      for (int i = 0; i < 4; i++) {
        int t4 = tb + 64*i;
        int blk = t4 ^ ((t4 >> 3) & 7);
        *reinterpret_cast<float4*>(&Kt[d*KTS + 4*blk]) = kst[i];
      }
    }
    __syncthreads();                      // Kt ready
    if (c < 47) {
      const int d = tid >> 6, tb = tid & 63;
      #pragma unroll
      for (int i = 0; i < 4; i++)
        kst[i] = *reinterpret_cast<const float4*>(
            kbuf + (size_t)(4*(c+1) + d)*16384 + b*1024 + 4*(tb + 64*i));
    }
    #pragma unroll
    for (int dl = 0; dl < 4; dl++) {
      const int d = 4*c + dl;
      float qv[8], kv[8];
      *reinterpret_cast<float4*>(&qv[0]) = *reinterpret_cast<const float4*>(&Qt[d*QTS + 8*ty]);
      *reinterpret_cast<float4*>(&qv[4]) = *reinterpret_cast<const float4*>(&Qt[d*QTS + 8*ty + 4]);
      *reinterpret_cast<float4*>(&kv[0]) = *reinterpret_cast<const float4*>(&Kt[dl*KTS + 4*kblk1]);
      *reinterpret_cast<float4*>(&kv[4]) = *reinterpret_cast<const float4*>(&Kt[dl*KTS + 4*kblk2]);
      #pragma unroll
      for (int r = 0; r < 8; r++)
        #pragma unroll
        for (int cc = 0; cc < 8; cc++)
          acc[r][cc] = fmaf(qv[r], kv[cc], acc[r][cc]);
    }
  }

  // -------- phase 2: scale + softmax + write attn probs --------
  #pragma unroll
  for (int r = 0; r < 8; r++)
    #pragma unroll
    for (int cc = 0; cc < 8; cc++) acc[r][cc] *= 0.5f;   // / sqrt(NQ)

  float* redm = red;
  float* redl = red + 32;
  const int wave = tid >> 6;
  #pragma unroll
  for (int r = 0; r < 8; r++) {
    float v = acc[r][0];
    #pragma unroll
    for (int cc = 1; cc < 8; cc++) v = fmaxf(v, acc[r][cc]);
    #pragma unroll
    for (int off = 32; off >= 1; off >>= 1) v = fmaxf(v, __shfl_xor(v, off));
    if ((tid & 63) == 0) redm[wave*8 + r] = v;
  }
  __syncthreads();
  float rowm[8];
  #pragma unroll
  for (int r = 0; r < 8; r++)
    rowm[r] = fmaxf(redm[(2*ty)*8 + r], redm[(2*ty+1)*8 + r]);
  #pragma unroll
  for (int r = 0; r < 8; r++) {
    float ssum = 0.f;
    #pragma unroll
    for (int cc = 0; cc < 8; cc++) {
      acc[r][cc] = expf(acc[r][cc] - rowm[r]);
      ssum += acc[r][cc];
    }
    #pragma unroll
    for (int off = 32; off >= 1; off >>= 1) ssum += __shfl_xor(ssum, off);
    if ((tid & 63) == 0) redl[wave*8 + r] = ssum;
  }
  __syncthreads();
  #pragma unroll
  for (int r = 0; r < 8; r++) {
    float inv = 1.f / (redl[(2*ty)*8 + r] + redl[(2*ty+1)*8 + r]);
    #pragma unroll
    for (int cc = 0; cc < 8; cc++) acc[r][cc] *= inv;
    size_t row = (size_t)b*1024 + s0 + 8*ty + r;
    float* dst = out_attn + row*1024 + 8*tx;
    *reinterpret_cast<float4*>(dst)     = make_float4(acc[r][0], acc[r][1], acc[r][2], acc[r][3]);
    *reinterpret_cast<float4*>(dst + 4) = make_float4(acc[r][4], acc[r][5], acc[r][6], acc[r][7]);
  }

  // -------- phase 3: PV from register probs via LDS Ps tiles --------
  const int ks = tid & 7;           // kk-slice: kk = 4*ks + kkl
  const int t3 = (tid >> 3) & 15;   // d-group: d = 12*t3 .. +11
  const int rg = tid >> 7;          // rows 8rg..8rg+7  (== ty)

  float acc_o[8][12];
  #pragma unroll
  for (int r = 0; r < 8; r++)
    #pragma unroll
    for (int e = 0; e < 12; e++) acc_o[r][e] = 0.f;

  float4 vst[6];
  {
    const float4* Vg4 = reinterpret_cast<const float4*>(vbuf + (size_t)b*1024*192);
    #pragma unroll
    for (int i = 0; i < 6; i++) vst[i] = Vg4[tid + 256*i];
  }

  for (int kc = 0; kc < 1024; kc += 32) {
    __syncthreads();                  // Vc/Ps free
    {
      // Vc fill, 16B-block XOR-swizzled by row (kk>>2) to spread bank quads
      #pragma unroll
      for (int i = 0; i < 6; i++) {
        int p = tid + 256*i;          // 0..1535 = kk*48 + bb
        int kk = p / 48, bb = p - kk*48;
        *reinterpret_cast<float4*>(&Vc[kk*192 + 4*(bb ^ (kk >> 2))]) = vst[i];
      }
    }
    // Ps owners: phase-1 threads whose cols fall in [kc, kc+32)
    if (tx >= (kc >> 3) && tx < (kc >> 3) + 4) {
      #pragma unroll
      for (int r = 0; r < 8; r++)
        #pragma unroll
        for (int cc = 0; cc < 8; cc++)
          Ps[(8*ty + r)*36 + (8*tx - kc) + cc] = acc[r][cc];
    }
    __syncthreads();                  // Vc/Ps ready
    if (kc + 32 < 1024) {
      const float4* Vg4 = reinterpret_cast<const float4*>(
          vbuf + (size_t)(b*1024 + kc + 32)*192);
      #pragma unroll
      for (int i = 0; i < 6; i++) vst[i] = Vg4[tid + 256*i];
    }
    // one b128 per row covers all 4 kkl (kk = 4*ks + kkl)
    float pvv[8][4];
    #pragma unroll
    for (int r = 0; r < 8; r++) {
      float4 t = *reinterpret_cast<const float4*>(&Ps[(8*rg + r)*36 + 4*ks]);
      pvv[r][0] = t.x; pvv[r][1] = t.y; pvv[r][2] = t.z; pvv[r][3] = t.w;
    }
    #pragma unroll
    for (int kkl = 0; kkl < 4; kkl++) {
      const int kk = 4*ks + kkl;
      float vv[12];
      #pragma unroll
      for (int j = 0; j < 3; j++)
        *reinterpret_cast<float4*>(&vv[4*j]) =
            *reinterpret_cast<const float4*>(&Vc[kk*192 + 4*((3*t3 + j) ^ ks)]);
      #pragma unroll
      for (int r = 0; r < 8; r++)
        #pragma unroll
        for (int e = 0; e < 12; e++)
          acc_o[r][e] = fmaf(pvv[r][kkl], vv[e], acc_o[r][e]);
    }
  }

  // reduce over the 8 kk-slices (lanes differing in bits 0-2)
  #pragma unroll
  for (int st = 1; st <= 4; st <<= 1)
    #pragma unroll
    for (int r = 0; r < 8; r++)
      #pragma unroll
      for (int e = 0; e < 12; e++)
        acc_o[r][e] += __shfl_xor(acc_o[r][e], st);

  // -------- phase 4: layernorm over D=192 --------
  if (ks == 0) {
    #pragma unroll
    for (int r = 0; r < 8; r++) {
      float sum = 0.f, sq = 0.f;
      #pragma unroll
      for (int e = 0; e < 12; e++) { sum += acc_o[r][e]; sq += acc_o[r][e]*acc_o[r][e]; }
      red[(8*rg + r)*32 + 2*t3]     = sum;
      red[(8*rg + r)*32 + 2*t3 + 1] = sq;
    }
  }
  __syncthreads();
  if (ks == 0) {
    float g[12], bt[12];
    #pragma unroll
    for (int j = 0; j < 3; j++) {
      *reinterpret_cast<float4*>(&g[4*j])  = *reinterpret_cast<const float4*>(&gamma[12*t3 + 4*j]);
      *reinterpret_cast<float4*>(&bt[4*j]) = *reinterpret_cast<const float4*>(&beta[12*t3 + 4*j]);
    }
    #pragma unroll
    for (int r = 0; r < 8; r++) {
      const int row = 8*rg + r;
      float sum = 0.f, sq = 0.f;
      #pragma unroll
      for (int u = 0; u < 16; u++) {
        sum += red[row*32 + 2*u];
        sq  += red[row*32 + 2*u + 1];
      }
      float mu  = sum * (1.f/192.f);
      float var = sq * (1.f/192.f) - mu*mu;
      float rstd = rsqrtf(var + 1e-5f);
      float* dst = out_o + ((size_t)b*1024 + s0 + row)*192 + 12*t3;
      #pragma unroll
      for (int j = 0; j < 3; j++) {
        float4 o4;
        o4.x = (acc_o[r][4*j+0]-mu)*rstd*g[4*j+0] + bt[4*j+0];
        o4.y = (acc_o[r][4*j+1]-mu)*rstd*g[4*j+1] + bt[4*j+1];
        o4.z = (acc_o[r][4*j+2]-mu)*rstd*g[4*j+2] + bt[4*j+2];
        o4.w = (acc_o[r][4*j+3]-mu)*rstd*g[4*j+3] + bt[4*j+3];
        *reinterpret_cast<float4*>(dst + 4*j) = o4;
      }
    }
  }
}

// =============================== launcher ===================================

extern "C" void kernel_launch(void* const* d_in, const int* in_sizes, int n_in,
                              void* d_out, int out_size, void* d_ws, size_t ws_size,
                              hipStream_t stream) {
  const float* x     = (const float*)d_in[0];
  const float* w     = (const float*)d_in[1];
  const float* ew    = (const float*)d_in[2];
  const float* tw    = (const float*)d_in[3];
  const float* gamma = (const float*)d_in[4];
  const float* beta  = (const float*)d_in[5];

  float* out_o    = (float*)d_out;                       // [16][1024][192]
  float* out_attn = out_o + (size_t)16*1024*192;         // [16][1024][1024]

  char* wsp = (char*)d_ws;
  float2* U   = (float2*)wsp;                            // 48*256 cplx = 96 KiB
  float* qbuf = (float*)(wsp + 98304);                   // [192][16384]
  float* kbuf = qbuf + (size_t)192*16384;                // [192][16384]
  float* vbuf = kbuf + (size_t)192*16384;                // [16384][192]

  build_unitaries<<<12, 64, 0, stream>>>(w, ew, tw, U);
  qkv_kernel<<<dim3(64, 48), 256, 0, stream>>>(x, U, qbuf, kbuf, vbuf);
  attn_kernel<<<dim3(16, 64), 256, 0, stream>>>(qbuf, kbuf, vbuf, gamma, beta,
                                                out_o, out_attn);
}